// Round 1
// baseline (2304.128 us; speedup 1.0000x reference)
//
#include <hip/hip_runtime.h>
#include <math.h>

#define D 64
constexpr float EPS_GATE = 1e-6f;
constexpr float EPS_BN   = 1e-5f;

// ---------------- K1: 4 fused node GEMMs: e_src, e_dst, Bh, Ax ----------------
__global__ __launch_bounds__(256) void k1_node_gemm(
    const float* __restrict__ nf,
    const float* __restrict__ Wsg, const float* __restrict__ bsg,
    const float* __restrict__ Wdg, const float* __restrict__ bdg,
    const float* __restrict__ Wdu, const float* __restrict__ bdu,
    const float* __restrict__ Wsu, const float* __restrict__ bsu,
    float* __restrict__ e_src, float* __restrict__ e_dst,
    float* __restrict__ Bh, float* __restrict__ Ax, int N)
{
    __shared__ float sW0[D*D], sW1[D*D], sW2[D*D], sW3[D*D];
    __shared__ float sB[4][D];
    int tid = threadIdx.x;
    for (int i = tid; i < D*D/4; i += 256) {
        ((float4*)sW0)[i] = ((const float4*)Wsg)[i];
        ((float4*)sW1)[i] = ((const float4*)Wdg)[i];
        ((float4*)sW2)[i] = ((const float4*)Wdu)[i];
        ((float4*)sW3)[i] = ((const float4*)Wsu)[i];
    }
    if (tid < D) { sB[0][tid]=bsg[tid]; sB[1][tid]=bdg[tid]; sB[2][tid]=bdu[tid]; sB[3][tid]=bsu[tid]; }
    __syncthreads();
    int lane = tid & 63;
    int gw = blockIdx.x * 4 + (tid >> 6);
    int nw = gridDim.x * 4;
    for (int n = gw; n < N; n += nw) {
        float row = nf[(size_t)n*D + lane];
        float a0 = sB[0][lane], a1 = sB[1][lane], a2 = sB[2][lane], a3 = sB[3][lane];
        #pragma unroll
        for (int k = 0; k < D; k++) {
            float xv = __shfl(row, k, 64);
            a0 += xv * sW0[k*D + lane];
            a1 += xv * sW1[k*D + lane];
            a2 += xv * sW2[k*D + lane];
            a3 += xv * sW3[k*D + lane];
        }
        size_t o = (size_t)n*D + lane;
        e_src[o] = a0; e_dst[o] = a1; Bh[o] = a2; Ax[o] = a3;
    }
}

// ---------------- K2: edge pass: m -> out_y slot, segment sums, BN stats(m) ----
__global__ __launch_bounds__(256) void k2_edge(
    const float* __restrict__ ef, const int* __restrict__ src, const int* __restrict__ dst,
    const float* __restrict__ We, const float* __restrict__ be,
    const float* __restrict__ e_src, const float* __restrict__ e_dst,
    const float* __restrict__ Bh,
    float* __restrict__ out_m,
    float* __restrict__ ssh, float* __restrict__ ss,
    float* __restrict__ stat_m, long E)
{
    __shared__ float sW[D*D];
    __shared__ float sB[D];
    __shared__ float sRed[4][D];
    int tid = threadIdx.x;
    for (int i = tid; i < D*D/4; i += 256)
        ((float4*)sW)[i] = ((const float4*)We)[i];
    if (tid < D) sB[tid] = be[tid];
    __syncthreads();
    int lane = tid & 63;
    int wid  = tid >> 6;
    long gw = (long)blockIdx.x * 4 + wid;
    long e0 = gw * 64;
    float psum = 0.f, psum2 = 0.f;
    if (e0 < E) {
        int nE = (int)((E - e0 < 64) ? (E - e0) : 64);
        int sv = (lane < nE) ? src[e0 + lane] : 0;
        int dv = (lane < nE) ? dst[e0 + lane] : 0;
        for (int i = 0; i < nE; i++) {
            long e = e0 + i;
            float er = ef[e*D + lane];
            float acc = sB[lane];
            #pragma unroll
            for (int k = 0; k < D; k++)
                acc += __shfl(er, k, 64) * sW[k*D + lane];
            int s = __shfl(sv, i, 64);
            int d = __shfl(dv, i, 64);
            float m = acc + e_src[(size_t)s*D + lane] + e_dst[(size_t)d*D + lane];
            out_m[e*D + lane] = m;
            float sg = 1.f / (1.f + __expf(-m));
            float bh = Bh[(size_t)s*D + lane];
            atomicAdd(&ssh[(size_t)d*D + lane], bh * sg);
            atomicAdd(&ss [(size_t)d*D + lane], sg);
            psum += m; psum2 += m*m;
        }
    }
    sRed[wid][lane] = psum;
    __syncthreads();
    if (wid == 0) {
        float t = sRed[0][lane] + sRed[1][lane] + sRed[2][lane] + sRed[3][lane];
        atomicAdd(&stat_m[lane], t);
    }
    __syncthreads();
    sRed[wid][lane] = psum2;
    __syncthreads();
    if (wid == 0) {
        float t = sRed[0][lane] + sRed[1][lane] + sRed[2][lane] + sRed[3][lane];
        atomicAdd(&stat_m[D + lane], t);
    }
}

// ---------------- K3: x_pre = Ax + h -> out_x slot, BN stats(x) ----------------
__global__ __launch_bounds__(256) void k3_node_pre(
    const float* __restrict__ Ax, const float* __restrict__ ssh, const float* __restrict__ ss,
    float* __restrict__ out_x, float* __restrict__ stat_x, int ND)
{
    __shared__ float sRed[4][D];
    int tid = threadIdx.x, lane = tid & 63, wid = tid >> 6;
    float psum = 0.f, psum2 = 0.f;
    for (int i = blockIdx.x*256 + tid; i < ND; i += gridDim.x*256) {
        float h  = ssh[i] / (ss[i] + EPS_GATE);
        float xp = Ax[i] + h;
        out_x[i] = xp;
        psum += xp; psum2 += xp*xp;
    }
    sRed[wid][lane] = psum;
    __syncthreads();
    if (wid == 0) {
        float t = sRed[0][lane] + sRed[1][lane] + sRed[2][lane] + sRed[3][lane];
        atomicAdd(&stat_x[lane], t);
    }
    __syncthreads();
    sRed[wid][lane] = psum2;
    __syncthreads();
    if (wid == 0) {
        float t = sRed[0][lane] + sRed[1][lane] + sRed[2][lane] + sRed[3][lane];
        atomicAdd(&stat_x[D + lane], t);
    }
}

// ---------------- K4: x = nf + silu(BN(x_pre)) in place ------------------------
__global__ __launch_bounds__(256) void k4_node_fin(
    const float* __restrict__ nf, const float* __restrict__ stat_x,
    const float* __restrict__ gamma, const float* __restrict__ beta,
    float* __restrict__ out_x, int ND, float invN)
{
    __shared__ float sSc[D], sSh[D];
    int tid = threadIdx.x;
    if (tid < D) {
        float mu  = stat_x[tid] * invN;
        float var = stat_x[D + tid] * invN - mu * mu;
        float rs  = rsqrtf(var + EPS_BN);
        float sc  = gamma[tid] * rs;
        sSc[tid] = sc;
        sSh[tid] = beta[tid] - mu * sc;
    }
    __syncthreads();
    for (int i = blockIdx.x*256 + tid; i < ND; i += gridDim.x*256) {
        int j = i & 63;
        float v = out_x[i] * sSc[j] + sSh[j];
        float sil = v / (1.f + __expf(-v));
        out_x[i] = nf[i] + sil;
    }
}

// ---------------- K5: y = ef + silu(BN(m)) in place (float4) --------------------
__global__ __launch_bounds__(256) void k5_edge_fin(
    const float* __restrict__ ef, const float* __restrict__ stat_m,
    const float* __restrict__ gamma, const float* __restrict__ beta,
    float* __restrict__ out_y, long ED, float invE)
{
    __shared__ float sSc[D], sSh[D];
    int tid = threadIdx.x;
    if (tid < D) {
        float mu  = stat_m[tid] * invE;
        float var = stat_m[D + tid] * invE - mu * mu;
        float rs  = rsqrtf(var + EPS_BN);
        float sc  = gamma[tid] * rs;
        sSc[tid] = sc;
        sSh[tid] = beta[tid] - mu * sc;
    }
    __syncthreads();
    long n4 = ED >> 2;
    for (long i = (long)blockIdx.x*256 + tid; i < n4; i += (long)gridDim.x*256) {
        float4 m4 = ((const float4*)out_y)[i];
        float4 e4 = ((const float4*)ef)[i];
        int j0 = ((int)(i & 15)) << 2;
        float4 r;
        float v;
        v = m4.x * sSc[j0+0] + sSh[j0+0]; r.x = e4.x + v / (1.f + __expf(-v));
        v = m4.y * sSc[j0+1] + sSh[j0+1]; r.y = e4.y + v / (1.f + __expf(-v));
        v = m4.z * sSc[j0+2] + sSh[j0+2]; r.z = e4.z + v / (1.f + __expf(-v));
        v = m4.w * sSc[j0+3] + sSh[j0+3]; r.w = e4.w + v / (1.f + __expf(-v));
        ((float4*)out_y)[i] = r;
    }
}

extern "C" void kernel_launch(void* const* d_in, const int* in_sizes, int n_in,
                              void* d_out, int out_size, void* d_ws, size_t ws_size,
                              hipStream_t stream)
{
    const float* nf  = (const float*)d_in[0];
    const float* ef  = (const float*)d_in[1];
    const int*   src = (const int*)  d_in[2];
    const int*   dst = (const int*)  d_in[3];
    const float* Wsg = (const float*)d_in[4];  const float* bsg = (const float*)d_in[5];
    const float* Wdg = (const float*)d_in[6];  const float* bdg = (const float*)d_in[7];
    const float* Weg = (const float*)d_in[8];  const float* beg = (const float*)d_in[9];
    const float* Wsu = (const float*)d_in[10]; const float* bsu = (const float*)d_in[11];
    const float* Wdu = (const float*)d_in[12]; const float* bdu = (const float*)d_in[13];
    const float* gn  = (const float*)d_in[14]; const float* bn  = (const float*)d_in[15];
    const float* ge  = (const float*)d_in[16]; const float* be_ = (const float*)d_in[17];

    int  N  = in_sizes[0] / D;
    long E  = in_sizes[1] / D;
    size_t ND = (size_t)N * D;
    long   ED = E * D;

    float* ws     = (float*)d_ws;
    float* e_src  = ws;
    float* e_dst  = ws + ND;
    float* Bh     = ws + 2*ND;
    float* Ax     = ws + 3*ND;
    float* ssh    = ws + 4*ND;
    float* ss     = ws + 5*ND;
    float* stat_m = ws + 6*ND;        // 128 floats
    float* stat_x = stat_m + 128;     // 128 floats

    float* out_x = (float*)d_out;
    float* out_y = out_x + ND;

    // zero accumulators (ssh, ss, stat_m, stat_x are contiguous)
    hipMemsetAsync(ssh, 0, (2*ND + 256) * sizeof(float), stream);

    k1_node_gemm<<<512, 256, 0, stream>>>(nf, Wsg,bsg, Wdg,bdg, Wdu,bdu, Wsu,bsu,
                                          e_src, e_dst, Bh, Ax, N);

    long nwaves = (E + 63) / 64;
    int  blocks2 = (int)((nwaves + 3) / 4);
    k2_edge<<<blocks2, 256, 0, stream>>>(ef, src, dst, Weg, beg,
                                         e_src, e_dst, Bh,
                                         out_y, ssh, ss, stat_m, E);

    k3_node_pre<<<1024, 256, 0, stream>>>(Ax, ssh, ss, out_x, stat_x, (int)ND);
    k4_node_fin<<<1024, 256, 0, stream>>>(nf, stat_x, gn, bn, out_x, (int)ND, 1.f/(float)N);
    k5_edge_fin<<<4096, 256, 0, stream>>>(ef, stat_m, ge, be_, out_y, ED, 1.f/(float)E);
}